// Round 3
// baseline (1011.192 us; speedup 1.0000x reference)
//
#include <hip/hip_runtime.h>
#include <cstdint>

typedef unsigned short u16;
typedef unsigned int u32;

#define N_TOKENS 8192
#define D_MODEL 1024
#define DIM_FF 4096
#define N_EXPERTS 8
#define MAX_SLOTS (N_TOKENS * 2)

typedef __bf16 bf16x8 __attribute__((ext_vector_type(8)));
typedef float f32x4 __attribute__((ext_vector_type(4)));

// ---------- helpers ----------
__device__ __forceinline__ u16 f2bf(float f) {
  u32 u = __float_as_uint(f);
  u32 r = (u + 0x7FFFu + ((u >> 16) & 1u)) >> 16;  // RNE
  return (u16)r;
}
__device__ __forceinline__ u16 bfc(float f) {
  __bf16 b = (__bf16)f;
  return __builtin_bit_cast(u16, b);
}

// async global->LDS, 16B per lane; LDS dst = wave-uniform base + lane*16
__device__ __forceinline__ void gl2lds16(const void* g, void* l) {
  __builtin_amdgcn_global_load_lds(
      (__attribute__((address_space(1))) void*)(g),
      (__attribute__((address_space(3))) void*)(l), 16, 0, 0);
}

__device__ __forceinline__ u32 lds_addr(const void* p) {
  return (u32)(uintptr_t)(__attribute__((address_space(3))) const void*)p;
}

__device__ __forceinline__ bf16x8 dsr128(u32 addr) {
  bf16x8 r;
  asm volatile("ds_read_b128 %0, %1" : "=v"(r) : "v"(addr));
  return r;
}

#define BARX() asm volatile("s_barrier" ::: "memory")
#define LGKM0() do { asm volatile("s_waitcnt lgkmcnt(0)" ::: "memory"); __builtin_amdgcn_sched_barrier(0); } while (0)
#define VMC(n) asm volatile("s_waitcnt vmcnt(" #n ")" ::: "memory")

// ---------- gate (+ fused x->bf16 cvt) ----------
__global__ __launch_bounds__(256) void gate_kernel(
    const float* __restrict__ x, const float* __restrict__ Wg,
    const float* __restrict__ bg, int* __restrict__ eidx,
    float* __restrict__ ew, u16* __restrict__ xb) {
  int tok = (int)((blockIdx.x * 256 + threadIdx.x) >> 6);
  int lane = threadIdx.x & 63;
  const float* xr = x + (size_t)tok * D_MODEL;
  u16* xbr = xb + (size_t)tok * D_MODEL;
  float acc[8] = {0.f, 0.f, 0.f, 0.f, 0.f, 0.f, 0.f, 0.f};
#pragma unroll
  for (int j = 0; j < 8; ++j) {
    int d = 2 * lane + 128 * j;
    float2 xv = *(const float2*)(xr + d);
    float4 wa0 = *(const float4*)(Wg + d * 8);
    float4 wb0 = *(const float4*)(Wg + d * 8 + 4);
    float4 wa1 = *(const float4*)(Wg + d * 8 + 8);
    float4 wb1 = *(const float4*)(Wg + d * 8 + 12);
    acc[0] += xv.x * wa0.x + xv.y * wa1.x;
    acc[1] += xv.x * wa0.y + xv.y * wa1.y;
    acc[2] += xv.x * wa0.z + xv.y * wa1.z;
    acc[3] += xv.x * wa0.w + xv.y * wa1.w;
    acc[4] += xv.x * wb0.x + xv.y * wb1.x;
    acc[5] += xv.x * wb0.y + xv.y * wb1.y;
    acc[6] += xv.x * wb0.z + xv.y * wb1.z;
    acc[7] += xv.x * wb0.w + xv.y * wb1.w;
    u32 pk = (u32)f2bf(xv.x) | ((u32)f2bf(xv.y) << 16);
    *(u32*)(xbr + d) = pk;
  }
#pragma unroll
  for (int off = 32; off > 0; off >>= 1) {
#pragma unroll
    for (int e = 0; e < 8; ++e) acc[e] += __shfl_xor(acc[e], off, 64);
  }
  if (lane == 0) {
    float p[8], m = -1e30f;
#pragma unroll
    for (int e = 0; e < 8; ++e) { p[e] = acc[e] + bg[e]; m = fmaxf(m, p[e]); }
    float s = 0.f;
#pragma unroll
    for (int e = 0; e < 8; ++e) { p[e] = __expf(p[e] - m); s += p[e]; }
#pragma unroll
    for (int e = 0; e < 8; ++e) p[e] /= s;
    int i0 = 0;
#pragma unroll
    for (int e = 1; e < 8; ++e) if (p[e] > p[i0]) i0 = e;
    int i1 = (i0 == 0) ? 1 : 0;
#pragma unroll
    for (int e = 0; e < 8; ++e) if (e != i0 && p[e] > p[i1]) i1 = e;
    float denom = p[i0] + p[i1] + 1e-9f;
    eidx[2 * tok] = i0; eidx[2 * tok + 1] = i1;
    ew[2 * tok] = p[i0] / denom; ew[2 * tok + 1] = p[i1] / denom;
  }
}

// ---------- count ----------
__global__ __launch_bounds__(256) void count_kernel(const int* __restrict__ eidx,
                                                    int* __restrict__ counts) {
  __shared__ int lc[16];
  int tid = threadIdx.x;
  if (tid < 16) lc[tid] = 0;
  __syncthreads();
  int t = blockIdx.x * 256 + tid;
  atomicAdd(&lc[2 * eidx[2 * t]], 1);
  atomicAdd(&lc[2 * eidx[2 * t + 1] + 1], 1);
  __syncthreads();
  if (tid < 16) atomicAdd(&counts[tid], lc[tid]);
}

// ---------- fill (+ tileMap build for 256-row slot tiles) ----------
__global__ __launch_bounds__(256) void fill_kernel(
    const int* __restrict__ eidx, const float* __restrict__ ew,
    const int* __restrict__ counts, int* __restrict__ fill,
    int* __restrict__ rowtok, float* __restrict__ rowwt,
    int* __restrict__ tmap) {
  __shared__ int lc[16];
  __shared__ int lbase[16];
  __shared__ int loff[16];
  int tid = threadIdx.x;
  if (tid < 16) lc[tid] = 0;
  __syncthreads();
  int t = blockIdx.x * 256 + tid;
  int e0 = eidx[2 * t], e1 = eidx[2 * t + 1];
  int p0 = atomicAdd(&lc[2 * e0], 1);
  int p1 = atomicAdd(&lc[2 * e1 + 1], 1);
  __syncthreads();
  if (tid < 16) lbase[tid] = atomicAdd(&fill[tid], lc[tid]);
  if (tid == 64) {
    int o = 0;
    for (int g = 0; g < 16; ++g) { loff[g] = o; o += counts[g]; }
  }
  if (blockIdx.x == 0 && tid == 128) {
    // tmap[0] = ntiles; entries: (expert<<16)|rtile. Sum ceil(cnt_e/256) <= 71.
    int nt2 = 0;
    for (int ee = 0; ee < N_EXPERTS; ++ee) {
      int c = counts[2 * ee] + counts[2 * ee + 1];
      int ntile = (c + 255) >> 8;
      for (int r = 0; r < ntile; ++r) tmap[1 + nt2++] = (ee << 16) | r;
    }
    tmap[0] = nt2;
  }
  __syncthreads();
  int pos0 = loff[2 * e0] + lbase[2 * e0] + p0;
  int pos1 = loff[2 * e1 + 1] + lbase[2 * e1 + 1] + p1;
  rowtok[pos0] = t; rowwt[pos0] = ew[2 * t];
  rowtok[pos1] = t; rowwt[pos1] = ew[2 * t + 1];
}

// ---------- per-expert transpose+convert: in [R][C] fp32 -> out [C][R] bf16 ----------
__global__ __launch_bounds__(256) void transpose_cvt(const float* __restrict__ in,
                                                     u16* __restrict__ out, int R, int C) {
  int e = blockIdx.z;
  const float* ip = in + (size_t)e * R * C;
  u16* op = out + (size_t)e * R * C;
  int c0 = blockIdx.x * 64, r0 = blockIdx.y * 64;
  __shared__ __align__(16) u16 t[64 * 68];
  int tid = threadIdx.x;
  int c4 = (tid & 15) * 4;
#pragma unroll
  for (int p = 0; p < 4; ++p) {
    int r = (tid >> 4) + 16 * p;
    float4 v = *(const float4*)(ip + (size_t)(r0 + r) * C + c0 + c4);
    uint2 pk;
    pk.x = (u32)bfc(v.x) | ((u32)bfc(v.y) << 16);
    pk.y = (u32)bfc(v.z) | ((u32)bfc(v.w) << 16);
    *(uint2*)&t[r * 68 + c4] = pk;
  }
  __syncthreads();
  int pair = tid >> 3;
  int r8 = (tid & 7) * 8;
  int c = 2 * pair;
  u32 u[8];
#pragma unroll
  for (int j = 0; j < 8; ++j) u[j] = *(const u32*)&t[(r8 + j) * 68 + c];
  uint4 lo, hi;
  lo.x = (u[0] & 0xffffu) | (u[1] << 16);
  lo.y = (u[2] & 0xffffu) | (u[3] << 16);
  lo.z = (u[4] & 0xffffu) | (u[5] << 16);
  lo.w = (u[6] & 0xffffu) | (u[7] << 16);
  hi.x = (u[0] >> 16) | (u[1] & 0xffff0000u);
  hi.y = (u[2] >> 16) | (u[3] & 0xffff0000u);
  hi.z = (u[4] >> 16) | (u[5] & 0xffff0000u);
  hi.w = (u[6] >> 16) | (u[7] & 0xffff0000u);
  *(uint4*)(op + (size_t)(c0 + c) * R + r0 + r8) = lo;
  *(uint4*)(op + (size_t)(c0 + c + 1) * R + r0 + r8) = hi;
}

// ======================================================================
// 256x256 8-phase GEMM core (m201 template, plain HIP):
//   BK=64, 512 thr = 8 waves (2M x 4N), per-wave 128x64 out, dbuf LDS 128KiB.
//   LDS bytes: A [2buf][256r][64k] @0..65536, B [2buf][256n][64k] @65536..131072.
//   Swizzle: 16B-chunk c stored at c^(row&7) (inverse-permuted global src,
//   same XOR on ds_read) -> conflict-free b128 column reads.
//   vmcnt(4) at phase 3/7 only (2 stages in flight); never 0 mid-loop.
// ======================================================================

// staging: sub=row-within-64-group, csrc = swizzled source chunk
#define STG_A(buf, h, ktv) do { \
  gl2lds16(aS##h##0 + (size_t)(ktv) * 64, lds + (buf) * 32768 + (h) * 16384 + 0 + tid * 16); \
  gl2lds16(aS##h##1 + (size_t)(ktv) * 64, lds + (buf) * 32768 + (h) * 16384 + 8192 + tid * 16); \
} while (0)
#define STG_B(buf, h, ktv) do { \
  gl2lds16(bS##h##0 + (size_t)(ktv) * 64, lds + 65536 + (buf) * 32768 + (h) * 16384 + 0 + tid * 16); \
  gl2lds16(bS##h##1 + (size_t)(ktv) * 64, lds + 65536 + (buf) * 32768 + (h) * 16384 + 8192 + tid * 16); \
} while (0)

#define RDA(DST, BO, QO) do { \
  _Pragma("unroll") \
  for (int mi_ = 0; mi_ < 4; ++mi_) { \
    DST[mi_][0] = dsr128(aR0 + (BO) + (QO) + mi_ * 2048); \
    DST[mi_][1] = dsr128(aR1 + (BO) + (QO) + mi_ * 2048); \
  } \
} while (0)
#define RDB(DST, BO, HO) do { \
  _Pragma("unroll") \
  for (int ni_ = 0; ni_ < 2; ++ni_) { \
    DST[ni_][0] = dsr128(bR0 + (BO) + (HO) + ni_ * 2048); \
    DST[ni_][1] = dsr128(bR1 + (BO) + (HO) + ni_ * 2048); \
  } \
} while (0)

#define QMM(MO, NO, AF, BF) do { \
  __builtin_amdgcn_s_setprio(1); \
  _Pragma("unroll") \
  for (int mi_ = 0; mi_ < 4; ++mi_) \
    _Pragma("unroll") \
    for (int ni_ = 0; ni_ < 2; ++ni_) \
      _Pragma("unroll") \
      for (int ks_ = 0; ks_ < 2; ++ks_) \
        acc[(MO) + mi_][(NO) + ni_] = __builtin_amdgcn_mfma_f32_16x16x32_bf16( \
            AF[mi_][ks_], BF[ni_][ks_], acc[(MO) + mi_][(NO) + ni_], 0, 0, 0); \
  __builtin_amdgcn_s_setprio(0); \
} while (0)

// one iteration = 2 K-tiles (buf0 then buf1), 8 phases
#define KITER(KT, NL) do { \
  /* ph0: buf0 Q00 */ \
  RDA(af, 0, 0); RDB(bl, 0, 0); \
  STG_A(1, 0, (KT) + 1); \
  BARX(); LGKM0(); \
  QMM(0, 0, af, bl); \
  BARX(); \
  /* ph1: buf0 Q01 */ \
  RDB(bh, 0, 4096); \
  STG_A(1, 1, (KT) + 1); \
  BARX(); LGKM0(); \
  QMM(0, 2, af, bh); \
  BARX(); \
  /* ph2: buf0 Q10 */ \
  RDA(ah, 0, 8192); \
  if (NL) STG_B(0, 0, (KT) + 2); \
  BARX(); LGKM0(); \
  QMM(4, 0, ah, bl); \
  BARX(); \
  /* ph3: buf0 Q11 + vmcnt */ \
  if (NL) { STG_B(0, 1, (KT) + 2); VMC(4); } else { VMC(0); } \
  BARX(); \
  QMM(4, 2, ah, bh); \
  BARX(); \
  /* ph4: buf1 Q00 */ \
  RDA(af, 32768, 0); RDB(bl, 32768, 0); \
  if (NL) STG_A(0, 0, (KT) + 2); \
  BARX(); LGKM0(); \
  QMM(0, 0, af, bl); \
  BARX(); \
  /* ph5: buf1 Q01 */ \
  RDB(bh, 32768, 4096); \
  if (NL) STG_A(0, 1, (KT) + 2); \
  BARX(); LGKM0(); \
  QMM(0, 2, af, bh); \
  BARX(); \
  /* ph6: buf1 Q10 */ \
  RDA(ah, 32768, 8192); \
  if (NL) STG_B(1, 0, (KT) + 3); \
  BARX(); LGKM0(); \
  QMM(4, 0, ah, bl); \
  BARX(); \
  /* ph7: buf1 Q11 + vmcnt */ \
  if (NL) { STG_B(1, 1, (KT) + 3); VMC(4); } \
  BARX(); \
  QMM(4, 2, ah, bh); \
  BARX(); \
} while (0)

// ---------- fc1: H[slot,f] = gelu(Xg @ W1 + b1), bf16, 256^2 8-phase ----------
__global__ __launch_bounds__(512) void fc1_kernel(
    const u16* __restrict__ xb, const u16* __restrict__ w1t,
    const float* __restrict__ b1, const int* __restrict__ rowtok,
    const int* __restrict__ counts, const int* __restrict__ tmap,
    u16* __restrict__ H) {
  const int bx = blockIdx.x;
  const int t = bx >> 4;     // slot tile
  const int ct = bx & 15;    // 256-col tile of DIM_FF
  if (t >= tmap[0]) return;
  const int ent = tmap[1 + t];
  const int e = ent >> 16;
  const int rt = ent & 0xffff;
  int base = 0;
#pragma unroll
  for (int g = 0; g < 16; ++g) base += (g < 2 * e) ? counts[g] : 0;
  const int count = counts[2 * e] + counts[2 * e + 1];

  extern __shared__ char lds[];
  const int tid = threadIdx.x;

  // staging sources (A gathered via rowtok, clamped; B = w1t rows)
  const int sub = tid >> 3;
  const int csrc = (tid & 7) ^ (sub & 7);
  const int lastslot = base + count - 1;
  const u16* wb = w1t + (size_t)e * ((size_t)DIM_FF * D_MODEL);
  int s00 = base + rt * 256 + 0 + sub;   if (s00 > lastslot) s00 = lastslot;
  int s01 = base + rt * 256 + 64 + sub;  if (s01 > lastslot) s01 = lastslot;
  int s10 = base + rt * 256 + 128 + sub; if (s10 > lastslot) s10 = lastslot;
  int s11 = base + rt * 256 + 192 + sub; if (s11 > lastslot) s11 = lastslot;
  const u16* aS00 = xb + (size_t)rowtok[s00] * D_MODEL + csrc * 8;
  const u16* aS01 = xb + (size_t)rowtok[s01] * D_MODEL + csrc * 8;
  const u16* aS10 = xb + (size_t)rowtok[s10] * D_MODEL + csrc * 8;
  const u16* aS11 = xb + (size_t)rowtok[s11] * D_MODEL + csrc * 8;
  const u16* bS00 = wb + (size_t)(ct * 256 + 0 + sub) * D_MODEL + csrc * 8;
  const u16* bS01 = wb + (size_t)(ct * 256 + 64 + sub) * D_MODEL + csrc * 8;
  const u16* bS10 = wb + (size_t)(ct * 256 + 128 + sub) * D_MODEL + csrc * 8;
  const u16* bS11 = wb + (size_t)(ct * 256 + 192 + sub) * D_MODEL + csrc * 8;

  // read-side swizzled bases
  const int lane = tid & 63, wid = tid >> 6;
  const int wm = wid & 1, wn = wid >> 1;
  const int lc = lane & 15, quad = lane >> 4;
  const u32 lb = lds_addr(lds);
  const u32 aR0 = lb + (u32)((wm * 128 + lc) * 128 + (((0 + quad) ^ (lc & 7)) * 16));
  const u32 aR1 = lb + (u32)((wm * 128 + lc) * 128 + (((4 + quad) ^ (lc & 7)) * 16));
  const u32 bR0 = lb + 65536u + (u32)((wn * 64 + lc) * 128 + (((0 + quad) ^ (lc & 7)) * 16));
  const u32 bR1 = lb + 65536u + (u32)((wn * 64 + lc) * 128 + (((4 + quad) ^ (lc & 7)) * 16));

  f32x4 acc[8][4];
#pragma unroll
  for (int i = 0; i < 8; ++i)
#pragma unroll
    for (int j = 0; j < 4; ++j) acc[i][j] = (f32x4)0.0f;
  bf16x8 af[4][2], ah[4][2], bl[2][2], bh[2][2];

  // prologue: buf0 <- kt0 (B,A), buf1 <- kt1 (B); A(kt1) staged in it0 ph0-1
  STG_B(0, 0, 0); STG_B(0, 1, 0); STG_A(0, 0, 0); STG_A(0, 1, 0);
  STG_B(1, 0, 1); STG_B(1, 1, 1);
  VMC(4); BARX();

  const int NITER = (D_MODEL / 64) / 2;  // 8
  for (int it = 0; it < NITER; ++it) {
    const int kt = 2 * it;
    const bool nl = (it < NITER - 1);
    KITER(kt, nl);
  }

  // epilogue: bias + exact-ish GELU -> bf16 H
  float bias[4];
#pragma unroll
  for (int ni = 0; ni < 4; ++ni) bias[ni] = b1[e * DIM_FF + ct * 256 + wn * 64 + ni * 16 + lc];
#pragma unroll
  for (int mi = 0; mi < 8; ++mi) {
#pragma unroll
    for (int r = 0; r < 4; ++r) {
      int grow = rt * 256 + wm * 128 + mi * 16 + quad * 4 + r;
      if (grow < count) {
        size_t rowbase = (size_t)(base + grow) * DIM_FF + ct * 256 + wn * 64;
#pragma unroll
        for (int ni = 0; ni < 4; ++ni) {
          float v = acc[mi][ni][r] + bias[ni];
          float t3 = v * (1.0f + 0.044715f * v * v);
          float u = __builtin_amdgcn_exp2f(fminf(2.302208f * t3, 80.0f));
          float h = v * u * __builtin_amdgcn_rcpf(u + 1.0f);
          H[rowbase + ni * 16 + lc] = f2bf(h);
        }
      }
    }
  }
}

// ---------- fc2: out[tok] += wt*(H @ W2 + b2), merged top1+2, ks-split x2 ----------
__global__ __launch_bounds__(512) void fc2_kernel(
    const u16* __restrict__ H, const u16* __restrict__ w2t,
    const float* __restrict__ b2, const int* __restrict__ rowtok,
    const float* __restrict__ rowwt, const int* __restrict__ counts,
    const int* __restrict__ tmap, float* __restrict__ out) {
  const int bx = blockIdx.x;
  const int t = bx >> 3;
  const int c8 = bx & 7;
  const int ct = c8 >> 1;   // 0..3 (256-col tile of D_MODEL)
  const int ks = c8 & 1;    // K half
  if (t >= tmap[0]) return;
  const int ent = tmap[1 + t];
  const int e = ent >> 16;
  const int rt = ent & 0xffff;
  int base = 0;
#pragma unroll
  for (int g = 0; g < 16; ++g) base += (g < 2 * e) ? counts[g] : 0;
  const int count = counts[2 * e] + counts[2 * e + 1];

  extern __shared__ char lds[];
  const int tid = threadIdx.x;

  const int sub = tid >> 3;
  const int csrc = (tid & 7) ^ (sub & 7);
  const u16* hb = H + (size_t)(base + rt * 256) * DIM_FF + (size_t)ks * (DIM_FF / 2) + csrc * 8;
  const u16* aS00 = hb + (size_t)(0 + sub) * DIM_FF;
  const u16* aS01 = hb + (size_t)(64 + sub) * DIM_FF;
  const u16* aS10 = hb + (size_t)(128 + sub) * DIM_FF;
  const u16* aS11 = hb + (size_t)(192 + sub) * DIM_FF;
  const u16* wb = w2t + (size_t)e * ((size_t)D_MODEL * DIM_FF) + (size_t)ks * (DIM_FF / 2) + csrc * 8;
  const u16* bS00 = wb + (size_t)(ct * 256 + 0 + sub) * DIM_FF;
  const u16* bS01 = wb + (size_t)(ct * 256 + 64 + sub) * DIM_FF;
  const u16* bS10 = wb + (size_t)(ct * 256 + 128 + sub) * DIM_FF;
  const u16* bS11 = wb + (size_t)(ct * 256 + 192 + sub) * DIM_FF;

  const int lane = tid & 63, wid = tid >> 6;
  const int wm = wid & 1, wn = wid >> 1;
  const int lc = lane & 15, quad = lane >> 4;
  const u32 lb = lds_addr(lds);
  const u32 aR0 = lb + (u32)((wm * 128 + lc) * 128 + (((0 + quad) ^ (lc & 7)) * 16));
  const u32 aR1 = lb + (u32)((wm * 128 + lc) * 128 + (((4 + quad) ^ (lc & 7)) * 16));
  const u32 bR0 = lb + 65536u + (u32)((wn * 64 + lc) * 128 + (((0 + quad) ^ (lc & 7)) * 16));
  const u32 bR1 = lb + 65536u + (u32)((wn * 64 + lc) * 128 + (((4 + quad) ^ (lc & 7)) * 16));

  f32x4 acc[8][4];
#pragma unroll
  for (int i = 0; i < 8; ++i)
#pragma unroll
    for (int j = 0; j < 4; ++j) acc[i][j] = (f32x4)0.0f;
  bf16x8 af[4][2], ah[4][2], bl[2][2], bh[2][2];

  STG_B(0, 0, 0); STG_B(0, 1, 0); STG_A(0, 0, 0); STG_A(0, 1, 0);
  STG_B(1, 0, 1); STG_B(1, 1, 1);
  VMC(4); BARX();

  const int NITER = ((DIM_FF / 2) / 64) / 2;  // 16
  for (int it = 0; it < NITER; ++it) {
    const int kt = 2 * it;
    const bool nl = (it < NITER - 1);
    KITER(kt, nl);
  }

  float bias[4];
#pragma unroll
  for (int ni = 0; ni < 4; ++ni)
    bias[ni] = (ks == 0) ? b2[e * D_MODEL + ct * 256 + wn * 64 + ni * 16 + lc] : 0.0f;
#pragma unroll
  for (int mi = 0; mi < 8; ++mi) {
#pragma unroll
    for (int r = 0; r < 4; ++r) {
      int grow = rt * 256 + wm * 128 + mi * 16 + quad * 4 + r;
      if (grow < count) {
        int slot = base + grow;
        float wt = rowwt[slot];
        float* orow = out + (size_t)rowtok[slot] * D_MODEL + ct * 256 + wn * 64;
#pragma unroll
        for (int ni = 0; ni < 4; ++ni)
          unsafeAtomicAdd(orow + ni * 16 + lc, wt * (acc[mi][ni][r] + bias[ni]));
      }
    }
  }
}

extern "C" void kernel_launch(void* const* d_in, const int* in_sizes, int n_in,
                              void* d_out, int out_size, void* d_ws, size_t ws_size,
                              hipStream_t stream) {
  (void)in_sizes; (void)n_in; (void)ws_size; (void)out_size;
  const float* x  = (const float*)d_in[0];
  const float* Wg = (const float*)d_in[1];
  const float* bg = (const float*)d_in[2];
  const float* W1 = (const float*)d_in[3];
  const float* b1 = (const float*)d_in[4];
  const float* W2 = (const float*)d_in[5];
  const float* b2 = (const float*)d_in[6];
  float* out = (float*)d_out;

  char* ws = (char*)d_ws;
  size_t off = 0;
  int*   counts  = (int*)(ws + 0);     // 16 ints
  int*   fill    = (int*)(ws + 128);   // 16 ints
  int*   tmap    = (int*)(ws + 256);   // 1 + 72 ints
  off = 4096;
  int*   eidx    = (int*)(ws + off); off += 65536;
  float* ew      = (float*)(ws + off); off += 65536;
  int*   rowtok  = (int*)(ws + off); off += 65536;
  float* rowwt   = (float*)(ws + off); off += 65536;
  u16*   xb      = (u16*)(ws + off); off += (size_t)N_TOKENS * D_MODEL * 2;
  u16*   w1t     = (u16*)(ws + off);
  u16*   w2t     = w1t;  // ALIASED: W2 transposed after fc1 finishes reading w1t
  off += (size_t)N_EXPERTS * DIM_FF * D_MODEL * 2;
  u16*   H       = (u16*)(ws + off);
  off += (size_t)(MAX_SLOTS + 256) * DIM_FF * 2;  // +256 rows: unguarded tail reads

  static int attr_done = 0;
  if (!attr_done) {
    hipFuncSetAttribute((const void*)fc1_kernel, hipFuncAttributeMaxDynamicSharedMemorySize, 131072);
    hipFuncSetAttribute((const void*)fc2_kernel, hipFuncAttributeMaxDynamicSharedMemorySize, 131072);
    attr_done = 1;
  }

  hipMemsetAsync(ws, 0, 4096, stream);
  hipMemsetAsync(out, 0, (size_t)N_TOKENS * D_MODEL * sizeof(float), stream);

  gate_kernel<<<N_TOKENS / 4, 256, 0, stream>>>(x, Wg, bg, eidx, ew, xb);
  count_kernel<<<N_TOKENS / 256, 256, 0, stream>>>(eidx, counts);
  fill_kernel<<<N_TOKENS / 256, 256, 0, stream>>>(eidx, ew, counts, fill, rowtok, rowwt, tmap);
  transpose_cvt<<<dim3(DIM_FF / 64, D_MODEL / 64, N_EXPERTS), 256, 0, stream>>>(W1, w1t, D_MODEL, DIM_FF);
  fc1_kernel<<<72 * 16, 512, 131072, stream>>>(xb, w1t, b1, rowtok, counts, tmap, H);
  transpose_cvt<<<dim3(D_MODEL / 64, DIM_FF / 64, N_EXPERTS), 256, 0, stream>>>(W2, w2t, DIM_FF, D_MODEL);
  fc2_kernel<<<72 * 8, 512, 131072, stream>>>(H, w2t, b2, rowtok, rowwt, counts, tmap, out);
}

// Round 4
// 814.895 us; speedup vs baseline: 1.2409x; 1.2409x over previous
//
#include <hip/hip_runtime.h>
#include <cstdint>

typedef unsigned short u16;
typedef unsigned int u32;

#define N_TOKENS 8192
#define D_MODEL 1024
#define DIM_FF 4096
#define N_EXPERTS 8
#define MAX_SLOTS (N_TOKENS * 2)

typedef __bf16 bf16x8 __attribute__((ext_vector_type(8)));
typedef float f32x4 __attribute__((ext_vector_type(4)));

// ---------- helpers ----------
__device__ __forceinline__ u16 f2bf(float f) {
  u32 u = __float_as_uint(f);
  u32 r = (u + 0x7FFFu + ((u >> 16) & 1u)) >> 16;  // RNE
  return (u16)r;
}
__device__ __forceinline__ u16 bfc(float f) {  // native cvt (RNE), 1 VALU op
  __bf16 b = (__bf16)f;
  return __builtin_bit_cast(u16, b);
}

// async global->LDS, 16B per lane; LDS dst = wave-uniform base + lane*16
__device__ __forceinline__ void gl2lds16(const void* g, void* l) {
  __builtin_amdgcn_global_load_lds(
      (__attribute__((address_space(1))) void*)(g),
      (__attribute__((address_space(3))) void*)(l), 16, 0, 0);
}

// ---------- gate (+ fused x->bf16 cvt): logits -> softmax -> top2 -> renorm ----------
__global__ __launch_bounds__(256) void gate_kernel(
    const float* __restrict__ x, const float* __restrict__ Wg,
    const float* __restrict__ bg, int* __restrict__ eidx,
    float* __restrict__ ew, u16* __restrict__ xb) {
  int tok = (int)((blockIdx.x * 256 + threadIdx.x) >> 6);
  int lane = threadIdx.x & 63;
  const float* xr = x + (size_t)tok * D_MODEL;
  u16* xbr = xb + (size_t)tok * D_MODEL;
  float acc[8] = {0.f, 0.f, 0.f, 0.f, 0.f, 0.f, 0.f, 0.f};
#pragma unroll
  for (int j = 0; j < 8; ++j) {
    int d = 2 * lane + 128 * j;
    float2 xv = *(const float2*)(xr + d);
    float4 wa0 = *(const float4*)(Wg + d * 8);
    float4 wb0 = *(const float4*)(Wg + d * 8 + 4);
    float4 wa1 = *(const float4*)(Wg + d * 8 + 8);
    float4 wb1 = *(const float4*)(Wg + d * 8 + 12);
    acc[0] += xv.x * wa0.x + xv.y * wa1.x;
    acc[1] += xv.x * wa0.y + xv.y * wa1.y;
    acc[2] += xv.x * wa0.z + xv.y * wa1.z;
    acc[3] += xv.x * wa0.w + xv.y * wa1.w;
    acc[4] += xv.x * wb0.x + xv.y * wb1.x;
    acc[5] += xv.x * wb0.y + xv.y * wb1.y;
    acc[6] += xv.x * wb0.z + xv.y * wb1.z;
    acc[7] += xv.x * wb0.w + xv.y * wb1.w;
    u32 pk = (u32)f2bf(xv.x) | ((u32)f2bf(xv.y) << 16);
    *(u32*)(xbr + d) = pk;  // lanes consecutive -> coalesced 256B/wave
  }
#pragma unroll
  for (int off = 32; off > 0; off >>= 1) {
#pragma unroll
    for (int e = 0; e < 8; ++e) acc[e] += __shfl_xor(acc[e], off, 64);
  }
  if (lane == 0) {
    float p[8], m = -1e30f;
#pragma unroll
    for (int e = 0; e < 8; ++e) { p[e] = acc[e] + bg[e]; m = fmaxf(m, p[e]); }
    float s = 0.f;
#pragma unroll
    for (int e = 0; e < 8; ++e) { p[e] = __expf(p[e] - m); s += p[e]; }
#pragma unroll
    for (int e = 0; e < 8; ++e) p[e] /= s;
    int i0 = 0;
#pragma unroll
    for (int e = 1; e < 8; ++e) if (p[e] > p[i0]) i0 = e;
    int i1 = (i0 == 0) ? 1 : 0;
#pragma unroll
    for (int e = 0; e < 8; ++e) if (e != i0 && p[e] > p[i1]) i1 = e;
    float denom = p[i0] + p[i1] + 1e-9f;
    eidx[2 * tok] = i0; eidx[2 * tok + 1] = i1;   // k=0: top-1, k=1: top-2
    ew[2 * tok] = p[i0] / denom; ew[2 * tok + 1] = p[i1] / denom;
  }
}

// ---------- count: per-block LDS histogram over (expert,rank) -> 16 atomics/block ----------
__global__ __launch_bounds__(256) void count_kernel(const int* __restrict__ eidx,
                                                    int* __restrict__ counts) {
  __shared__ int lc[16];
  int tid = threadIdx.x;
  if (tid < 16) lc[tid] = 0;
  __syncthreads();
  int t = blockIdx.x * 256 + tid;
  atomicAdd(&lc[2 * eidx[2 * t]], 1);          // rank 0
  atomicAdd(&lc[2 * eidx[2 * t + 1] + 1], 1);  // rank 1
  __syncthreads();
  if (tid < 16) atomicAdd(&counts[tid], lc[tid]);
}

// ---------- fill: block-aggregated range claiming; prefix recomputed locally ----------
__global__ __launch_bounds__(256) void fill_kernel(
    const int* __restrict__ eidx, const float* __restrict__ ew,
    const int* __restrict__ counts, int* __restrict__ fill,
    int* __restrict__ rowtok, float* __restrict__ rowwt) {
  __shared__ int lc[16];
  __shared__ int lbase[16];
  __shared__ int loff[16];
  int tid = threadIdx.x;
  if (tid < 16) lc[tid] = 0;
  __syncthreads();
  int t = blockIdx.x * 256 + tid;
  int e0 = eidx[2 * t], e1 = eidx[2 * t + 1];
  int p0 = atomicAdd(&lc[2 * e0], 1);
  int p1 = atomicAdd(&lc[2 * e1 + 1], 1);
  __syncthreads();
  if (tid < 16) lbase[tid] = atomicAdd(&fill[tid], lc[tid]);
  if (tid == 64) {  // different wave than the atomics: runs concurrently
    int o = 0;
    for (int g = 0; g < 16; ++g) { loff[g] = o; o += counts[g]; }
  }
  __syncthreads();
  int pos0 = loff[2 * e0] + lbase[2 * e0] + p0;
  int pos1 = loff[2 * e1 + 1] + lbase[2 * e1 + 1] + p1;
  rowtok[pos0] = t; rowwt[pos0] = ew[2 * t];
  rowtok[pos1] = t; rowwt[pos1] = ew[2 * t + 1];
}

// ---------- per-expert transpose+convert: in [R][C] fp32 -> out [C][R] bf16 ----------
__global__ __launch_bounds__(256) void transpose_cvt(const float* __restrict__ in,
                                                     u16* __restrict__ out, int R, int C) {
  int e = blockIdx.z;
  const float* ip = in + (size_t)e * R * C;
  u16* op = out + (size_t)e * R * C;
  int c0 = blockIdx.x * 64, r0 = blockIdx.y * 64;
  __shared__ __align__(16) u16 t[64 * 68];  // [r][c], pitch 68 u16 = 136 B (8B-mult)
  int tid = threadIdx.x;
  int c4 = (tid & 15) * 4;
#pragma unroll
  for (int p = 0; p < 4; ++p) {
    int r = (tid >> 4) + 16 * p;
    float4 v = *(const float4*)(ip + (size_t)(r0 + r) * C + c0 + c4);
    uint2 pk;
    pk.x = (u32)bfc(v.x) | ((u32)bfc(v.y) << 16);
    pk.y = (u32)bfc(v.z) | ((u32)bfc(v.w) << 16);
    *(uint2*)&t[r * 68 + c4] = pk;
  }
  __syncthreads();
  int pair = tid >> 3;        // 0..31 -> output row pair (c, c+1)
  int r8 = (tid & 7) * 8;     // 8 lanes * 16B = 128B contiguous stores
  int c = 2 * pair;
  u32 u[8];
#pragma unroll
  for (int j = 0; j < 8; ++j) u[j] = *(const u32*)&t[(r8 + j) * 68 + c];
  uint4 lo, hi;
  lo.x = (u[0] & 0xffffu) | (u[1] << 16);
  lo.y = (u[2] & 0xffffu) | (u[3] << 16);
  lo.z = (u[4] & 0xffffu) | (u[5] << 16);
  lo.w = (u[6] & 0xffffu) | (u[7] << 16);
  hi.x = (u[0] >> 16) | (u[1] & 0xffff0000u);
  hi.y = (u[2] >> 16) | (u[3] & 0xffff0000u);
  hi.z = (u[4] >> 16) | (u[5] & 0xffff0000u);
  hi.w = (u[6] >> 16) | (u[7] & 0xffff0000u);
  *(uint4*)(op + (size_t)(c0 + c) * R + r0 + r8) = lo;
  *(uint4*)(op + (size_t)(c0 + c + 1) * R + r0 + r8) = hi;
}

// ======================================================================
// 2-phase 128x128 GEMM cores, BK=64 (vs R0's 32): half the barrier drains
// per FLOP; 32 MFMAs per K-step. LDS 32 KiB/block (still >=4 blocks/CU).
// Fragment reads XOR-swizzled both-sides (validated R3, zero conflicts):
//   store: linear dst, source chunk pre-permuted by (row&7)
//   read : chunk = (ks*4+quad) ^ (lc&7)
// ======================================================================

// ---------- fc1: H[slot,f] = gelu(Xg @ W1 + b1), bf16 ----------
__global__ __launch_bounds__(256) void fc1_kernel(
    const u16* __restrict__ xb, const u16* __restrict__ w1t,
    const float* __restrict__ b1, const int* __restrict__ rowtok,
    const int* __restrict__ counts, u16* __restrict__ H) {
  const int b = blockIdx.x;
  const int e = b & 7;
  const int lin = b >> 3;      // 0..2047
  const int rt = lin & 63;     // rt-fast: consecutive active blocks share B col
  const int ct = lin >> 6;     // 0..31
  int base = 0;
#pragma unroll
  for (int g = 0; g < 16; ++g) base += (g < 2 * e) ? counts[g] : 0;
  const int count = counts[2 * e] + counts[2 * e + 1];
  if (rt * 128 >= count) return;

  __shared__ __align__(16) __bf16 As[128 * 64];  // [row][64k], 16 KiB
  __shared__ __align__(16) __bf16 Bs[128 * 64];

  const int tid = threadIdx.x;
  const int lane = tid & 63;
  const int wave = tid >> 6;

  // staging: thread covers (row = tid>>3 + 32p, chunk = tid&7), 4 passes
  const int srow = tid >> 3;             // 0..31
  const int schunk = tid & 7;
  const int sx = ((schunk ^ (srow & 7)) * 8);  // swizzled source elem offset
  const int lastslot = base + count - 1;
  const u16* gA[4];
  const u16* gB[4];
  const u16* wb = w1t + (size_t)e * DIM_FF * D_MODEL + (size_t)(ct * 128) * D_MODEL;
#pragma unroll
  for (int p = 0; p < 4; ++p) {
    int s = base + rt * 128 + srow + 32 * p;
    if (s > lastslot) s = lastslot;
    gA[p] = xb + (size_t)rowtok[s] * D_MODEL + sx;
    gB[p] = wb + (size_t)(srow + 32 * p) * D_MODEL + sx;
  }

  const int wm = (wave & 1) * 64;
  const int wn = (wave >> 1) * 64;
  const int quad = lane >> 4;
  const int lc = lane & 15;
  const int cx0 = ((0 + quad) ^ (lc & 7)) * 8;  // ks=0 swizzled chunk
  const int cx1 = ((4 + quad) ^ (lc & 7)) * 8;  // ks=1
  const __bf16* Ap = As + (wm + lc) * 64;
  const __bf16* Bp = Bs + (wn + lc) * 64;

  f32x4 acc[4][4];
#pragma unroll
  for (int i = 0; i < 4; ++i)
#pragma unroll
    for (int j = 0; j < 4; ++j) acc[i][j] = (f32x4)0.0f;

  for (int kt = 0; kt < D_MODEL / 64; ++kt) {  // 16 iters
#pragma unroll
    for (int p = 0; p < 4; ++p) {
      gl2lds16(gA[p] + (size_t)kt * 64, (char*)As + p * 4096 + tid * 16);
      gl2lds16(gB[p] + (size_t)kt * 64, (char*)Bs + p * 4096 + tid * 16);
    }
    __syncthreads();
    bf16x8 af[4], bfr[4];
#pragma unroll
    for (int mi = 0; mi < 4; ++mi) af[mi] = *(const bf16x8*)(Ap + mi * 16 * 64 + cx0);
#pragma unroll
    for (int ni = 0; ni < 4; ++ni) bfr[ni] = *(const bf16x8*)(Bp + ni * 16 * 64 + cx0);
#pragma unroll
    for (int mi = 0; mi < 4; ++mi)
#pragma unroll
      for (int ni = 0; ni < 4; ++ni)
        acc[mi][ni] = __builtin_amdgcn_mfma_f32_16x16x32_bf16(af[mi], bfr[ni], acc[mi][ni], 0, 0, 0);
#pragma unroll
    for (int mi = 0; mi < 4; ++mi) af[mi] = *(const bf16x8*)(Ap + mi * 16 * 64 + cx1);
#pragma unroll
    for (int ni = 0; ni < 4; ++ni) bfr[ni] = *(const bf16x8*)(Bp + ni * 16 * 64 + cx1);
#pragma unroll
    for (int mi = 0; mi < 4; ++mi)
#pragma unroll
      for (int ni = 0; ni < 4; ++ni)
        acc[mi][ni] = __builtin_amdgcn_mfma_f32_16x16x32_bf16(af[mi], bfr[ni], acc[mi][ni], 0, 0, 0);
    __syncthreads();
  }

  float bias[4];
#pragma unroll
  for (int ni = 0; ni < 4; ++ni) bias[ni] = b1[e * DIM_FF + ct * 128 + wn + ni * 16 + lc];
#pragma unroll
  for (int mi = 0; mi < 4; ++mi) {
#pragma unroll
    for (int r = 0; r < 4; ++r) {
      int m = wm + mi * 16 + quad * 4 + r;
      int grow = rt * 128 + m;
      if (grow < count) {
        size_t rowbase = (size_t)(base + grow) * DIM_FF + ct * 128 + wn;
#pragma unroll
        for (int ni = 0; ni < 4; ++ni) {
          float v = acc[mi][ni][r] + bias[ni];
          // tanh-form GELU via exp2+rcp; max abs err ~3e-4 (<< bf16 rounding of H)
          float t3 = v * (1.0f + 0.044715f * v * v);
          float u = __builtin_amdgcn_exp2f(fminf(2.302208f * t3, 80.0f));
          float h = v * u * __builtin_amdgcn_rcpf(u + 1.0f);
          H[rowbase + ni * 16 + lc] = f2bf(h);
        }
      }
    }
  }
}

// ---------- fc2: pass kpass=0 (top-1 slots): out[tok] = wt*(H@W2 + b2) plain store
//             pass kpass=1 (top-2 slots): out[tok] += wt*(...)  plain RMW ----------
__global__ __launch_bounds__(256) void fc2_kernel(
    const u16* __restrict__ H, const u16* __restrict__ w2t,
    const float* __restrict__ b2, const int* __restrict__ rowtok,
    const float* __restrict__ rowwt, const int* __restrict__ counts,
    float* __restrict__ out, int kpass) {
  const int b = blockIdx.x;
  const int e = b & 7;
  const int lin = b >> 3;      // 0..511
  const int rt = lin & 63;
  const int ct = lin >> 6;     // 0..7
  int base = 0;
#pragma unroll
  for (int g = 0; g < 16; ++g) base += (g < 2 * e + kpass) ? counts[g] : 0;
  const int cnt = counts[2 * e + kpass];
  if (rt * 128 >= cnt) return;

  __shared__ __align__(16) __bf16 As[128 * 64];
  __shared__ __align__(16) __bf16 Bs[128 * 64];

  const int tid = threadIdx.x;
  const int lane = tid & 63;
  const int wave = tid >> 6;

  const int srow = tid >> 3;
  const int schunk = tid & 7;
  const int sx = ((schunk ^ (srow & 7)) * 8);
  const u16* gA[4];
  const u16* gB[4];
  const u16* hb = H + (size_t)(base + rt * 128) * DIM_FF;        // contiguous slots (+pad)
  const u16* wb = w2t + (size_t)e * D_MODEL * DIM_FF + (size_t)(ct * 128) * DIM_FF;
#pragma unroll
  for (int p = 0; p < 4; ++p) {
    gA[p] = hb + (size_t)(srow + 32 * p) * DIM_FF + sx;
    gB[p] = wb + (size_t)(srow + 32 * p) * DIM_FF + sx;
  }

  const int wm = (wave & 1) * 64;
  const int wn = (wave >> 1) * 64;
  const int quad = lane >> 4;
  const int lc = lane & 15;
  const int cx0 = ((0 + quad) ^ (lc & 7)) * 8;
  const int cx1 = ((4 + quad) ^ (lc & 7)) * 8;
  const __bf16* Ap = As + (wm + lc) * 64;
  const __bf16* Bp = Bs + (wn + lc) * 64;

  f32x4 acc[4][4];
#pragma unroll
  for (int i = 0; i < 4; ++i)
#pragma unroll
    for (int j = 0; j < 4; ++j) acc[i][j] = (f32x4)0.0f;

  for (int kt = 0; kt < DIM_FF / 64; ++kt) {  // 64 iters
#pragma unroll
    for (int p = 0; p < 4; ++p) {
      gl2lds16(gA[p] + (size_t)kt * 64, (char*)As + p * 4096 + tid * 16);
      gl2lds16(gB[p] + (size_t)kt * 64, (char*)Bs + p * 4096 + tid * 16);
    }
    __syncthreads();
    bf16x8 af[4], bfr[4];
#pragma unroll
    for (int mi = 0; mi < 4; ++mi) af[mi] = *(const bf16x8*)(Ap + mi * 16 * 64 + cx0);
#pragma unroll
    for (int ni = 0; ni < 4; ++ni) bfr[ni] = *(const bf16x8*)(Bp + ni * 16 * 64 + cx0);
#pragma unroll
    for (int mi = 0; mi < 4; ++mi)
#pragma unroll
      for (int ni = 0; ni < 4; ++ni)
        acc[mi][ni] = __builtin_amdgcn_mfma_f32_16x16x32_bf16(af[mi], bfr[ni], acc[mi][ni], 0, 0, 0);
#pragma unroll
    for (int mi = 0; mi < 4; ++mi) af[mi] = *(const bf16x8*)(Ap + mi * 16 * 64 + cx1);
#pragma unroll
    for (int ni = 0; ni < 4; ++ni) bfr[ni] = *(const bf16x8*)(Bp + ni * 16 * 64 + cx1);
#pragma unroll
    for (int mi = 0; mi < 4; ++mi)
#pragma unroll
      for (int ni = 0; ni < 4; ++ni)
        acc[mi][ni] = __builtin_amdgcn_mfma_f32_16x16x32_bf16(af[mi], bfr[ni], acc[mi][ni], 0, 0, 0);
    __syncthreads();
  }

  float bias[4];
#pragma unroll
  for (int ni = 0; ni < 4; ++ni) bias[ni] = b2[e * D_MODEL + ct * 128 + wn + ni * 16 + lc];

#pragma unroll
  for (int mi = 0; mi < 4; ++mi) {
#pragma unroll
    for (int r = 0; r < 4; ++r) {
      int m = wm + mi * 16 + quad * 4 + r;
      int grow = rt * 128 + m;
      if (grow < cnt) {
        int slot = base + grow;
        float wt = rowwt[slot];
        float* orow = out + (size_t)rowtok[slot] * D_MODEL + ct * 128 + wn;
        if (kpass == 0) {
#pragma unroll
          for (int ni = 0; ni < 4; ++ni)
            orow[ni * 16 + lc] = wt * (acc[mi][ni][r] + bias[ni]);
        } else {
#pragma unroll
          for (int ni = 0; ni < 4; ++ni)
            orow[ni * 16 + lc] += wt * (acc[mi][ni][r] + bias[ni]);
        }
      }
    }
  }
}

extern "C" void kernel_launch(void* const* d_in, const int* in_sizes, int n_in,
                              void* d_out, int out_size, void* d_ws, size_t ws_size,
                              hipStream_t stream) {
  (void)in_sizes; (void)n_in; (void)ws_size; (void)out_size;
  const float* x  = (const float*)d_in[0];
  const float* Wg = (const float*)d_in[1];
  const float* bg = (const float*)d_in[2];
  const float* W1 = (const float*)d_in[3];
  const float* b1 = (const float*)d_in[4];
  const float* W2 = (const float*)d_in[5];
  const float* b2 = (const float*)d_in[6];
  float* out = (float*)d_out;

  char* ws = (char*)d_ws;
  size_t off = 0;
  int*   counts  = (int*)(ws + 0);     // 16 ints
  int*   fill    = (int*)(ws + 128);   // 16 ints
  off = 4096;
  int*   eidx    = (int*)(ws + off); off += 65536;
  float* ew      = (float*)(ws + off); off += 65536;
  int*   rowtok  = (int*)(ws + off); off += 65536;
  float* rowwt   = (float*)(ws + off); off += 65536;
  u16*   xb      = (u16*)(ws + off); off += (size_t)N_TOKENS * D_MODEL * 2;
  u16*   w1t     = (u16*)(ws + off);
  u16*   w2t     = w1t;  // ALIASED: W2 transposed after fc1 finishes reading w1t
  off += (size_t)N_EXPERTS * DIM_FF * D_MODEL * 2;
  u16*   H       = (u16*)(ws + off);
  off += (size_t)(MAX_SLOTS + 128) * DIM_FF * 2;  // +128 rows: unguarded tail reads
  // total ~216 MB

  hipMemsetAsync(ws, 0, 4096, stream);

  gate_kernel<<<N_TOKENS / 4, 256, 0, stream>>>(x, Wg, bg, eidx, ew, xb);
  count_kernel<<<N_TOKENS / 256, 256, 0, stream>>>(eidx, counts);
  fill_kernel<<<N_TOKENS / 256, 256, 0, stream>>>(eidx, ew, counts, fill, rowtok, rowwt);
  transpose_cvt<<<dim3(DIM_FF / 64, D_MODEL / 64, N_EXPERTS), 256, 0, stream>>>(W1, w1t, D_MODEL, DIM_FF);
  fc1_kernel<<<N_EXPERTS * (DIM_FF / 128) * 64, 256, 0, stream>>>(xb, w1t, b1, rowtok, counts, H);
  transpose_cvt<<<dim3(D_MODEL / 64, DIM_FF / 64, N_EXPERTS), 256, 0, stream>>>(W2, w2t, DIM_FF, D_MODEL);
  fc2_kernel<<<N_EXPERTS * (D_MODEL / 128) * 64, 256, 0, stream>>>(H, w2t, b2, rowtok, rowwt, counts, out, 0);
  fc2_kernel<<<N_EXPERTS * (D_MODEL / 128) * 64, 256, 0, stream>>>(H, w2t, b2, rowtok, rowwt, counts, out, 1);
}